// Round 19
// baseline (2880.903 us; speedup 1.0000x reference)
//
#include <hip/hip_runtime.h>

// Only the temporal (LSTM) branch of the reference reaches the output
// (h_gcn is dead). Per node:
//   xt_s = x[n, 52+s] * W_tp + b_tp          (rank-1, folded into A0/C0)
//   2-layer LSTM (H=32, T=12, torch gate order i,f,g,o)
//   out[n] = relu(h1 @ W_fc1 + b_fc1) @ W_fc2 + b_fc2
//
// v12: s=8 k-split (8 lanes/node, 4-float slices) x 2 nodes/lane.
//   Model (v10/v11 data): LDS is a per-CU pipe @~12cyc/ds_read_b128.
//   v10 (4 FMA/load) floor ~1125us, measured 1242 (90%). v11 (8 FMA/load)
//   halved the stream (busy 630us) but VGPR=168 collapsed occupancy.
//   v12 keeps 8 FMA/load and cuts registers: per-node state/lane = 4
//   floats -> 2-node state = 40 regs total (h,c,hn all in regs,
//   arithmetic provenance -> no remat). LDS = weights only (48 KB) ->
//   2 blocks x 8 waves = 16 waves/CU at the <=128 VGPR tier.
//   Reduction = rs8 reduce-scatter (xor 4,2,1); owner lane u holds
//   j = 4u+jj, matching its h-slice [4u,4u+4) -> commit stays local.
//   LDS floor ~562us; VALU ~340us; target 750-950us.
// Tells: VGPR>=160 -> hoisting (shrink windows); hbm>>10MB -> spill;
// flat dur + low VALUBusy + no spill -> I$ streaming (44KB t-body).

#define TSTEPS 12
#define BS 512               // 8 waves per block
#define NPB 128              // nodes per block (64 slots x 2 nodes)

__device__ __forceinline__ float fsig(float x) {
    float e = __expf(-x);                      // v_exp path; e in [0, inf)
    return __builtin_amdgcn_rcpf(1.0f + e);    // 1/(1+e), ~1 ulp
}

__device__ __forceinline__ float ftanh(float x) {
    float ax = fabsf(x);
    float e = __expf(-2.0f * ax);              // in (0,1], no overflow
    float r = (1.0f - e) * __builtin_amdgcn_rcpf(1.0f + e);
    return x < 0.0f ? -r : r;
}

// Repacked fold of layer-0 input matmul + biases, per OUTPUT j:
//   ws[j*8 + {0..3}] = A0 for gates i,f,g,o of j   (A0[r]=dot(Wih0[r,:],W_tp))
//   ws[j*8 + {4..7}] = C0 for gates i,f,g,o of j   (C0[r]=dot(Wih0[r,:],b_tp)+bih0[r]+bhh0[r])
//   ws[256 + j*4 + {0..3}] = C1 gates i,f,g,o      (bih1[r]+bhh1[r])
// where r = gate*32 + j.
__global__ void precomp_kernel(const float* __restrict__ Wih0,
                               const float* __restrict__ Wtp,
                               const float* __restrict__ btp,
                               const float* __restrict__ bih0,
                               const float* __restrict__ bhh0,
                               const float* __restrict__ bih1,
                               const float* __restrict__ bhh1,
                               float* __restrict__ ws) {
    int r = threadIdx.x;   // 0..127
    if (r < 128) {
        float a = 0.0f, c = 0.0f;
#pragma unroll
        for (int k = 0; k < 16; ++k) {
            float w = Wih0[r * 16 + k];
            a += w * Wtp[k];
            c += w * btp[k];
        }
        const int g4 = r >> 5;          // gate 0..3 (i,f,g,o)
        const int j  = r & 31;          // output index
        ws[j * 8 + g4]       = a;
        ws[j * 8 + 4 + g4]   = c + bih0[r] + bhh0[r];
        ws[256 + j * 4 + g4] = bih1[r] + bhh1[r];
    }
}

__device__ __forceinline__ float dot4(const float4 w, const float h[4]) {
    return w.x*h[0] + w.y*h[1] + w.z*h[2] + w.w*h[3];
}

// Reduce-scatter over 8 lanes (one node's lane group, contiguous tids):
// input p[g] = partial for target lane g; returns full sum for g = u.
__device__ __forceinline__ float rs8(const float p[8],
                                     bool b4, bool b2, bool b1) {
    float k0 = b4 ? p[4] : p[0], s0 = b4 ? p[0] : p[4];
    float k1 = b4 ? p[5] : p[1], s1 = b4 ? p[1] : p[5];
    float k2 = b4 ? p[6] : p[2], s2 = b4 ? p[2] : p[6];
    float k3 = b4 ? p[7] : p[3], s3 = b4 ? p[3] : p[7];
    k0 += __shfl_xor(s0, 4); k1 += __shfl_xor(s1, 4);
    k2 += __shfl_xor(s2, 4); k3 += __shfl_xor(s3, 4);
    float m0 = b2 ? k2 : k0, t0 = b2 ? k0 : k2;
    float m1 = b2 ? k3 : k1, t1 = b2 ? k1 : k3;
    m0 += __shfl_xor(t0, 2); m1 += __shfl_xor(t1, 2);
    float r = b1 ? m1 : m0,  q = b1 ? m0 : m1;
    return r + __shfl_xor(q, 1);
}

__global__ __launch_bounds__(BS) void lstm_kernel(
    const float* __restrict__ x,
    const float* __restrict__ Whh0,   // [128,32]
    const float* __restrict__ Wih1,   // [128,32]
    const float* __restrict__ Whh1,   // [128,32]
    const float* __restrict__ Wfc1,   // [32,16]
    const float* __restrict__ bfc1,   // [16]
    const float* __restrict__ Wfc2,   // [16]
    const float* __restrict__ bfc2,   // [1]
    const float* __restrict__ pre,    // [384] from precomp (repacked)
    float* __restrict__ out, int N)
{
    // 48 KB weights only: [0:4096) Whh0, [4096:8192) Wih1, [8192:12288)
    // Whh1, row-major [128][32]. ds_read addrs: 8 distinct 16B slots per
    // wave (u*16B), broadcast across slots -> conflict-free.
    __shared__ __align__(16) float sW[12288];

    const int tid = threadIdx.x;
#pragma unroll
    for (int i = 0; i < 8; ++i) sW[i * BS + tid]        = Whh0[i * BS + tid];
#pragma unroll
    for (int i = 0; i < 8; ++i) sW[4096 + i * BS + tid] = Wih1[i * BS + tid];
#pragma unroll
    for (int i = 0; i < 8; ++i) sW[8192 + i * BS + tid] = Whh1[i * BS + tid];
    __syncthreads();                    // only barrier in the kernel

    const int u    = tid & 7;           // lane within node group; k-slice
    const int slot = tid >> 3;          // 0..63
    const int so4  = u * 4;             // slice base (floats)
    const bool b4 = (u & 4) != 0, b2 = (u & 2) != 0, b1 = (u & 1) != 0;
    const int nA = blockIdx.x * NPB + slot;         // node A
    const int nB = nA + 64;                         // node B
    const int nnA = (nA < N) ? nA : (N > 0 ? N - 1 : 0);
    const int nnB = (nB < N) ? nB : (N > 0 ? N - 1 : 0);
    const float* xrA = x + (size_t)nnA * 64 + 52;   // last 12 features
    const float* xrB = x + (size_t)nnB * 64 + 52;

    // ALL state in registers (arithmetic/shfl provenance -> no remat):
    // lane u owns k-slice AND j-range [4u, 4u+4) of both nodes.
    float h0A[4], h0B[4], h1A[4], h1B[4];
    float c0A[4], c0B[4], c1A[4], c1B[4];
    float hnA[4], hnB[4];
#pragma unroll
    for (int k = 0; k < 4; ++k) {
        h0A[k] = 0.0f; h0B[k] = 0.0f; h1A[k] = 0.0f; h1B[k] = 0.0f;
        c0A[k] = 0.0f; c0B[k] = 0.0f; c1A[k] = 0.0f; c1B[k] = 0.0f;
    }

#pragma unroll 1
    for (int t = 0; t < TSTEPS; ++t) {
        const float xvA = xrA[t];
        const float xvB = xrB[t];

        // ---------------- layer 0 ----------------
#pragma unroll
        for (int jj = 0; jj < 4; ++jj) {
            float SA[4], SB[4];
#pragma unroll
            for (int gate = 0; gate < 4; ++gate) {   // 8-load window
                float4 w[8];
#pragma unroll
                for (int g = 0; g < 8; ++g)
                    w[g] = *(const float4*)&sW[(gate * 32 + g * 4 + jj) * 32 + so4];
                float pA[8], pB[8];
#pragma unroll
                for (int g = 0; g < 8; ++g) {        // each load: 2 nodes
                    pA[g] = dot4(w[g], h0A);
                    pB[g] = dot4(w[g], h0B);
                }
                SA[gate] = rs8(pA, b4, b2, b1);
                SB[gate] = rs8(pB, b4, b2, b1);
                __builtin_amdgcn_sched_barrier(0);   // cap load window
            }
            const int jown = so4 + jj;               // this lane's j
            const float4 pAq = ((const float4*)pre)[jown * 2];       // A0
            const float4 pCq = ((const float4*)pre)[jown * 2 + 1];   // C0
            {   // node A finish
                const float gi = SA[0] + pCq.x + xvA * pAq.x;
                const float gf = SA[1] + pCq.y + xvA * pAq.y;
                const float gG = SA[2] + pCq.z + xvA * pAq.z;
                const float go = SA[3] + pCq.w + xvA * pAq.w;
                const float cc = fsig(gf) * c0A[jj] + fsig(gi) * ftanh(gG);
                c0A[jj] = cc;
                hnA[jj] = fsig(go) * ftanh(cc);
            }
            {   // node B finish
                const float gi = SB[0] + pCq.x + xvB * pAq.x;
                const float gf = SB[1] + pCq.y + xvB * pAq.y;
                const float gG = SB[2] + pCq.z + xvB * pAq.z;
                const float go = SB[3] + pCq.w + xvB * pAq.w;
                const float cc = fsig(gf) * c0B[jj] + fsig(gi) * ftanh(gG);
                c0B[jj] = cc;
                hnB[jj] = fsig(go) * ftanh(cc);
            }
        }
#pragma unroll
        for (int k = 0; k < 4; ++k) { h0A[k] = hnA[k]; h0B[k] = hnB[k]; }

        // ---------------- layer 1 ----------------
#pragma unroll
        for (int jj = 0; jj < 4; ++jj) {
            float SA[4], SB[4];
#pragma unroll
            for (int gate = 0; gate < 4; ++gate) {
                float pA[8], pB[8];
                {   // a-chunk: Wih1 . h0 (8 loads)
                    float4 w[8];
#pragma unroll
                    for (int g = 0; g < 8; ++g)
                        w[g] = *(const float4*)&sW[4096 + (gate * 32 + g * 4 + jj) * 32 + so4];
#pragma unroll
                    for (int g = 0; g < 8; ++g) {
                        pA[g] = dot4(w[g], h0A);
                        pB[g] = dot4(w[g], h0B);
                    }
                }
                __builtin_amdgcn_sched_barrier(0);
                {   // b-chunk: Whh1 . h1 (8 loads)
                    float4 w[8];
#pragma unroll
                    for (int g = 0; g < 8; ++g)
                        w[g] = *(const float4*)&sW[8192 + (gate * 32 + g * 4 + jj) * 32 + so4];
#pragma unroll
                    for (int g = 0; g < 8; ++g) {
                        pA[g] += dot4(w[g], h1A);
                        pB[g] += dot4(w[g], h1B);
                    }
                }
                SA[gate] = rs8(pA, b4, b2, b1);
                SB[gate] = rs8(pB, b4, b2, b1);
                __builtin_amdgcn_sched_barrier(0);
            }
            const int jown = so4 + jj;
            const float4 pD = ((const float4*)(pre + 256))[jown];    // C1
            {   // node A finish
                const float gi = SA[0] + pD.x;
                const float gf = SA[1] + pD.y;
                const float gG = SA[2] + pD.z;
                const float go = SA[3] + pD.w;
                const float cc = fsig(gf) * c1A[jj] + fsig(gi) * ftanh(gG);
                c1A[jj] = cc;
                hnA[jj] = fsig(go) * ftanh(cc);
            }
            {   // node B finish
                const float gi = SB[0] + pD.x;
                const float gf = SB[1] + pD.y;
                const float gG = SB[2] + pD.z;
                const float go = SB[3] + pD.w;
                const float cc = fsig(gf) * c1B[jj] + fsig(gi) * ftanh(gG);
                c1B[jj] = cc;
                hnB[jj] = fsig(go) * ftanh(cc);
            }
        }
#pragma unroll
        for (int k = 0; k < 4; ++k) { h1A[k] = hnA[k]; h1B[k] = hnB[k]; }
    }

    // epilogue: relu(h1 @ Wfc1 + bfc1) @ Wfc2 + bfc2; h1 sliced over 8
    // lanes (rows [4u,4u+4)), reduce with xor 1,2,4.
    {
        float am[16];
#pragma unroll
        for (int m = 0; m < 16; ++m) am[m] = 0.0f;
#pragma unroll 1
        for (int kk = 0; kk < 4; ++kk) {
            const float* row = Wfc1 + (size_t)(so4 + kk) * 16;
            const float4 r0 = ((const float4*)row)[0];
            const float4 r1 = ((const float4*)row)[1];
            const float4 r2 = ((const float4*)row)[2];
            const float4 r3 = ((const float4*)row)[3];
            const float hv = h1A[kk];
            am[ 0] += r0.x*hv; am[ 1] += r0.y*hv; am[ 2] += r0.z*hv; am[ 3] += r0.w*hv;
            am[ 4] += r1.x*hv; am[ 5] += r1.y*hv; am[ 6] += r1.z*hv; am[ 7] += r1.w*hv;
            am[ 8] += r2.x*hv; am[ 9] += r2.y*hv; am[10] += r2.z*hv; am[11] += r2.w*hv;
            am[12] += r3.x*hv; am[13] += r3.y*hv; am[14] += r3.z*hv; am[15] += r3.w*hv;
        }
        float acc = bfc2[0];
#pragma unroll
        for (int m = 0; m < 16; ++m) {
            float a = am[m];
            a += __shfl_xor(a, 1); a += __shfl_xor(a, 2); a += __shfl_xor(a, 4);
            acc += fmaxf(a + bfc1[m], 0.0f) * Wfc2[m];
        }
        if (u == 0 && nA < N) out[nA] = acc;
    }
    {
        float am[16];
#pragma unroll
        for (int m = 0; m < 16; ++m) am[m] = 0.0f;
#pragma unroll 1
        for (int kk = 0; kk < 4; ++kk) {
            const float* row = Wfc1 + (size_t)(so4 + kk) * 16;
            const float4 r0 = ((const float4*)row)[0];
            const float4 r1 = ((const float4*)row)[1];
            const float4 r2 = ((const float4*)row)[2];
            const float4 r3 = ((const float4*)row)[3];
            const float hv = h1B[kk];
            am[ 0] += r0.x*hv; am[ 1] += r0.y*hv; am[ 2] += r0.z*hv; am[ 3] += r0.w*hv;
            am[ 4] += r1.x*hv; am[ 5] += r1.y*hv; am[ 6] += r1.z*hv; am[ 7] += r1.w*hv;
            am[ 8] += r2.x*hv; am[ 9] += r2.y*hv; am[10] += r2.z*hv; am[11] += r2.w*hv;
            am[12] += r3.x*hv; am[13] += r3.y*hv; am[14] += r3.z*hv; am[15] += r3.w*hv;
        }
        float acc = bfc2[0];
#pragma unroll
        for (int m = 0; m < 16; ++m) {
            float a = am[m];
            a += __shfl_xor(a, 1); a += __shfl_xor(a, 2); a += __shfl_xor(a, 4);
            acc += fmaxf(a + bfc1[m], 0.0f) * Wfc2[m];
        }
        if (u == 0 && nB < N) out[nB] = acc;
    }
}

extern "C" void kernel_launch(void* const* d_in, const int* in_sizes, int n_in,
                              void* d_out, int out_size, void* d_ws, size_t ws_size,
                              hipStream_t stream) {
    (void)n_in; (void)out_size; (void)ws_size;
    // setup_inputs() order:
    // 0 x, 1 edge_index, 2 W_fp, 3 b_fp, 4 W_g1, 5 b_g1, 6 W_g2, 7 b_g2,
    // 8 W_g3, 9 b_g3, 10 W_tp, 11 b_tp, 12 Wih0, 13 Whh0, 14 bih0, 15 bhh0,
    // 16 Wih1, 17 Whh1, 18 bih1, 19 bhh1, 20 W_fc1, 21 b_fc1, 22 W_fc2, 23 b_fc2
    const float* x    = (const float*)d_in[0];
    const float* Wtp  = (const float*)d_in[10];
    const float* btp  = (const float*)d_in[11];
    const float* Wih0 = (const float*)d_in[12];
    const float* Whh0 = (const float*)d_in[13];
    const float* bih0 = (const float*)d_in[14];
    const float* bhh0 = (const float*)d_in[15];
    const float* Wih1 = (const float*)d_in[16];
    const float* Whh1 = (const float*)d_in[17];
    const float* bih1 = (const float*)d_in[18];
    const float* bhh1 = (const float*)d_in[19];
    const float* Wfc1 = (const float*)d_in[20];
    const float* bfc1 = (const float*)d_in[21];
    const float* Wfc2 = (const float*)d_in[22];
    const float* bfc2 = (const float*)d_in[23];

    float* out = (float*)d_out;
    float* pre = (float*)d_ws;   // 384 floats (repacked per-j layout)

    const int N = in_sizes[0] / 64;

    precomp_kernel<<<1, 128, 0, stream>>>(Wih0, Wtp, btp, bih0, bhh0, bih1, bhh1, pre);
    lstm_kernel<<<(N + NPB - 1) / NPB, BS, 0, stream>>>(
        x, Whh0, Wih1, Whh1, Wfc1, bfc1, Wfc2, bfc2, pre, out, N);
}

// Round 21
// 1510.867 us; speedup vs baseline: 1.9068x; 1.9068x over previous
//
#include <hip/hip_runtime.h>

// Only the temporal (LSTM) branch of the reference reaches the output
// (h_gcn is dead). Per node:
//   xt_s = x[n, 52+s] * W_tp + b_tp          (rank-1, folded into A0/C0)
//   2-layer LSTM (H=32, T=12, torch gate order i,f,g,o)
//   out[n] = relu(h1 @ W_fc1 + b_fc1) @ W_fc2 + b_fc2
//
// v13 = v11 (quad k-split, 2 nodes/lane, 8 FMA/ds_read_b128) with window
// liveness halved to fit the 128-VGPR tier:
//   - v11: 8-load windows -> VGPR=168 -> 9% occupancy -> 1407 us (but
//     busy 630 us proved the halved stream).
//   - v12: deeper k-split -> more partials -> 128-cap spill, 2880 us.
//   - v13: two 4-load k-half windows per gate (window regs 32->16),
//     everything else = v11. Natural need ~117; __launch_bounds__(256,4)
//     caps at 128 to stop the v11-style drift to 168 (cap > need, so no
//     v2-style forced spill).
//   LDS 80 KB (48 weights + 32 c-state) -> 2 blocks x 4 waves = 8
//   waves/CU at the <=128 tier. LDS-instr floor ~560 us, VALU ~630 us.
// Tells: VGPR>=150 or hbm>>50MB or dur>=1242 -> line exhausted, v10 final.
// (Resubmission: round-20 bench failed on GPU acquisition, no measurement.)

#define TSTEPS 12
#define BS 256               // 4 waves per block
#define NPB 128              // nodes per block (64 slots x 2 nodes)

__device__ __forceinline__ float fsig(float x) {
    float e = __expf(-x);                      // v_exp path; e in [0, inf)
    return __builtin_amdgcn_rcpf(1.0f + e);    // 1/(1+e), ~1 ulp
}

__device__ __forceinline__ float ftanh(float x) {
    float ax = fabsf(x);
    float e = __expf(-2.0f * ax);              // in (0,1], no overflow
    float r = (1.0f - e) * __builtin_amdgcn_rcpf(1.0f + e);
    return x < 0.0f ? -r : r;
}

// Repacked fold of layer-0 input matmul + biases, per OUTPUT j:
//   ws[j*8 + {0..3}] = A0 for gates i,f,g,o of j   (A0[r]=dot(Wih0[r,:],W_tp))
//   ws[j*8 + {4..7}] = C0 for gates i,f,g,o of j   (C0[r]=dot(Wih0[r,:],b_tp)+bih0[r]+bhh0[r])
//   ws[256 + j*4 + {0..3}] = C1 gates i,f,g,o      (bih1[r]+bhh1[r])
// where r = gate*32 + j.
__global__ void precomp_kernel(const float* __restrict__ Wih0,
                               const float* __restrict__ Wtp,
                               const float* __restrict__ btp,
                               const float* __restrict__ bih0,
                               const float* __restrict__ bhh0,
                               const float* __restrict__ bih1,
                               const float* __restrict__ bhh1,
                               float* __restrict__ ws) {
    int r = threadIdx.x;   // 0..127
    if (r < 128) {
        float a = 0.0f, c = 0.0f;
#pragma unroll
        for (int k = 0; k < 16; ++k) {
            float w = Wih0[r * 16 + k];
            a += w * Wtp[k];
            c += w * btp[k];
        }
        const int g4 = r >> 5;          // gate 0..3 (i,f,g,o)
        const int j  = r & 31;          // output index
        ws[j * 8 + g4]       = a;
        ws[j * 8 + 4 + g4]   = c + bih0[r] + bhh0[r];
        ws[256 + j * 4 + g4] = bih1[r] + bhh1[r];
    }
}

__device__ __forceinline__ float dot4a(const float4 w, const float* h) {
    return w.x*h[0] + w.y*h[1] + w.z*h[2] + w.w*h[3];
}

// Reduce-scatter over a quad: inputs v0..v3 (per-g partials, all lanes),
// returns sum over the 4 lanes of v_s (s = lane&3). hi2=(s&2), hi1=(s&1).
__device__ __forceinline__ float rs4(float v0, float v1, float v2, float v3,
                                     bool hi2, bool hi1) {
    float sa = hi2 ? v0 : v2;     // give away first-of-other-pair
    float ka = hi2 ? v2 : v0;     // keep first-of-own-pair (g = s&2)
    float sb = hi2 ? v1 : v3;
    float kb = hi2 ? v3 : v1;     // g = (s&2)+1
    float u0 = ka + __shfl_xor(sa, 2);
    float u1 = kb + __shfl_xor(sb, 2);
    float sc = hi1 ? u0 : u1;
    float kc = hi1 ? u1 : u0;     // g = s
    return kc + __shfl_xor(sc, 1);
}

__global__ __launch_bounds__(BS, 4) void lstm_kernel(
    const float* __restrict__ x,
    const float* __restrict__ Whh0,   // [128,32]
    const float* __restrict__ Wih1,   // [128,32]
    const float* __restrict__ Whh1,   // [128,32]
    const float* __restrict__ Wfc1,   // [32,16]
    const float* __restrict__ bfc1,   // [16]
    const float* __restrict__ Wfc2,   // [16]
    const float* __restrict__ bfc2,   // [1]
    const float* __restrict__ pre,    // [384] from precomp (repacked)
    float* __restrict__ out, int N)
{
    // 48 KB weights + 16 KB c0 + 16 KB c1 (2 nodes x 8 per thread) = 80 KB.
    __shared__ __align__(16) float sW[12288];
    __shared__ float sc0[16 * BS];    // [jj*BS+tid] node A, [2048+...] node B
    __shared__ float sc1[16 * BS];

    const int tid = threadIdx.x;
#pragma unroll
    for (int i = 0; i < 16; ++i) sW[i * BS + tid]        = Whh0[i * BS + tid];
#pragma unroll
    for (int i = 0; i < 16; ++i) sW[4096 + i * BS + tid] = Wih1[i * BS + tid];
#pragma unroll
    for (int i = 0; i < 16; ++i) sW[8192 + i * BS + tid] = Whh1[i * BS + tid];
#pragma unroll
    for (int jj = 0; jj < 8; ++jj) {   // own columns only, no extra sync
        sc0[jj * BS + tid] = 0.0f;  sc0[2048 + jj * BS + tid] = 0.0f;
        sc1[jj * BS + tid] = 0.0f;  sc1[2048 + jj * BS + tid] = 0.0f;
    }
    __syncthreads();                    // only barrier in the kernel

    const int s    = tid & 3;           // k-slice / j-group 0..3
    const int slot = tid >> 2;          // 0..63 within block
    const int so8  = s * 8;             // slice base (floats)
    const bool hi2 = (s & 2) != 0;
    const bool hi1 = (s & 1) != 0;
    const int nA = blockIdx.x * NPB + slot;         // node A
    const int nB = nA + 64;                         // node B
    const int nnA = (nA < N) ? nA : (N > 0 ? N - 1 : 0);
    const int nnB = (nB < N) ? nB : (N > 0 ? N - 1 : 0);
    const float* xrA = x + (size_t)nnA * 64 + 52;   // last 12 features
    const float* xrB = x + (size_t)nnB * 64 + 52;

    // Per-lane register state for TWO nodes. c lives in LDS.
    float h0A[8], h0B[8], h1A[8], h1B[8], hnA[8], hnB[8];
#pragma unroll
    for (int k = 0; k < 8; ++k) { h0A[k] = 0.0f; h0B[k] = 0.0f; h1A[k] = 0.0f; h1B[k] = 0.0f; }

#pragma unroll 1
    for (int t = 0; t < TSTEPS; ++t) {
        const float xvA = xrA[t];
        const float xvB = xrB[t];

        // ---------------- layer 0 ----------------
#pragma unroll
        for (int jj = 0; jj < 8; ++jj) {
            const int jown = so8 + jj;
            float SA[4], SB[4];
#pragma unroll
            for (int gate = 0; gate < 4; ++gate) {
                float pA[4], pB[4];
                {   // k-half 0: 4-load window
                    float4 w[4];
#pragma unroll
                    for (int g = 0; g < 4; ++g)
                        w[g] = *(const float4*)&sW[(gate * 32 + g * 8 + jj) * 32 + so8];
#pragma unroll
                    for (int g = 0; g < 4; ++g) {
                        pA[g] = dot4a(w[g], h0A);
                        pB[g] = dot4a(w[g], h0B);
                    }
                }
                __builtin_amdgcn_sched_barrier(0);
                {   // k-half 1
                    float4 w[4];
#pragma unroll
                    for (int g = 0; g < 4; ++g)
                        w[g] = *(const float4*)&sW[(gate * 32 + g * 8 + jj) * 32 + so8 + 4];
#pragma unroll
                    for (int g = 0; g < 4; ++g) {
                        pA[g] += dot4a(w[g], h0A + 4);
                        pB[g] += dot4a(w[g], h0B + 4);
                    }
                }
                SA[gate] = rs4(pA[0], pA[1], pA[2], pA[3], hi2, hi1);
                SB[gate] = rs4(pB[0], pB[1], pB[2], pB[3], hi2, hi1);
                __builtin_amdgcn_sched_barrier(0);
            }
            const float4 pAq = ((const float4*)pre)[jown * 2];       // A0 quad
            const float4 pCq = ((const float4*)pre)[jown * 2 + 1];   // C0 quad
            {   // node A finish
                const float gi = SA[0] + pCq.x + xvA * pAq.x;
                const float gf = SA[1] + pCq.y + xvA * pAq.y;
                const float gG = SA[2] + pCq.z + xvA * pAq.z;
                const float go = SA[3] + pCq.w + xvA * pAq.w;
                const int ci = jj * BS + tid;
                const float cc = fsig(gf) * sc0[ci] + fsig(gi) * ftanh(gG);
                sc0[ci] = cc;
                hnA[jj] = fsig(go) * ftanh(cc);
            }
            {   // node B finish
                const float gi = SB[0] + pCq.x + xvB * pAq.x;
                const float gf = SB[1] + pCq.y + xvB * pAq.y;
                const float gG = SB[2] + pCq.z + xvB * pAq.z;
                const float go = SB[3] + pCq.w + xvB * pAq.w;
                const int ci = 2048 + jj * BS + tid;
                const float cc = fsig(gf) * sc0[ci] + fsig(gi) * ftanh(gG);
                sc0[ci] = cc;
                hnB[jj] = fsig(go) * ftanh(cc);
            }
        }
#pragma unroll
        for (int k = 0; k < 8; ++k) { h0A[k] = hnA[k]; h0B[k] = hnB[k]; }

        // ---------------- layer 1 ----------------
#pragma unroll
        for (int jj = 0; jj < 8; ++jj) {
            const int jown = so8 + jj;
            float SA[4], SB[4];
#pragma unroll
            for (int gate = 0; gate < 4; ++gate) {
                float pA[4], pB[4];
                {   // a-chunk half 0: Wih1 . h0[0:4]
                    float4 w[4];
#pragma unroll
                    for (int g = 0; g < 4; ++g)
                        w[g] = *(const float4*)&sW[4096 + (gate * 32 + g * 8 + jj) * 32 + so8];
#pragma unroll
                    for (int g = 0; g < 4; ++g) {
                        pA[g] = dot4a(w[g], h0A);
                        pB[g] = dot4a(w[g], h0B);
                    }
                }
                __builtin_amdgcn_sched_barrier(0);
                {   // a-chunk half 1
                    float4 w[4];
#pragma unroll
                    for (int g = 0; g < 4; ++g)
                        w[g] = *(const float4*)&sW[4096 + (gate * 32 + g * 8 + jj) * 32 + so8 + 4];
#pragma unroll
                    for (int g = 0; g < 4; ++g) {
                        pA[g] += dot4a(w[g], h0A + 4);
                        pB[g] += dot4a(w[g], h0B + 4);
                    }
                }
                __builtin_amdgcn_sched_barrier(0);
                {   // b-chunk half 0: Whh1 . h1[0:4]
                    float4 w[4];
#pragma unroll
                    for (int g = 0; g < 4; ++g)
                        w[g] = *(const float4*)&sW[8192 + (gate * 32 + g * 8 + jj) * 32 + so8];
#pragma unroll
                    for (int g = 0; g < 4; ++g) {
                        pA[g] += dot4a(w[g], h1A);
                        pB[g] += dot4a(w[g], h1B);
                    }
                }
                __builtin_amdgcn_sched_barrier(0);
                {   // b-chunk half 1
                    float4 w[4];
#pragma unroll
                    for (int g = 0; g < 4; ++g)
                        w[g] = *(const float4*)&sW[8192 + (gate * 32 + g * 8 + jj) * 32 + so8 + 4];
#pragma unroll
                    for (int g = 0; g < 4; ++g) {
                        pA[g] += dot4a(w[g], h1A + 4);
                        pB[g] += dot4a(w[g], h1B + 4);
                    }
                }
                SA[gate] = rs4(pA[0], pA[1], pA[2], pA[3], hi2, hi1);
                SB[gate] = rs4(pB[0], pB[1], pB[2], pB[3], hi2, hi1);
                __builtin_amdgcn_sched_barrier(0);
            }
            const float4 pD = ((const float4*)(pre + 256))[jown];   // C1 quad
            {   // node A finish
                const float gi = SA[0] + pD.x;
                const float gf = SA[1] + pD.y;
                const float gG = SA[2] + pD.z;
                const float go = SA[3] + pD.w;
                const int ci = jj * BS + tid;
                const float cc = fsig(gf) * sc1[ci] + fsig(gi) * ftanh(gG);
                sc1[ci] = cc;
                hnA[jj] = fsig(go) * ftanh(cc);
            }
            {   // node B finish
                const float gi = SB[0] + pD.x;
                const float gf = SB[1] + pD.y;
                const float gG = SB[2] + pD.z;
                const float go = SB[3] + pD.w;
                const int ci = 2048 + jj * BS + tid;
                const float cc = fsig(gf) * sc1[ci] + fsig(gi) * ftanh(gG);
                sc1[ci] = cc;
                hnB[jj] = fsig(go) * ftanh(cc);
            }
        }
#pragma unroll
        for (int k = 0; k < 8; ++k) { h1A[k] = hnA[k]; h1B[k] = hnB[k]; }
    }

    // epilogue: relu(h1 @ Wfc1 + bfc1) @ Wfc2 + bfc2, node A then node B
    {
        float am[16];
#pragma unroll
        for (int m = 0; m < 16; ++m) am[m] = 0.0f;
#pragma unroll 1
        for (int kk = 0; kk < 8; ++kk) {
            const float* row = Wfc1 + (size_t)(so8 + kk) * 16;
            const float4 r0 = ((const float4*)row)[0];
            const float4 r1 = ((const float4*)row)[1];
            const float4 r2 = ((const float4*)row)[2];
            const float4 r3 = ((const float4*)row)[3];
            const float hv = h1A[kk];
            am[ 0] += r0.x*hv; am[ 1] += r0.y*hv; am[ 2] += r0.z*hv; am[ 3] += r0.w*hv;
            am[ 4] += r1.x*hv; am[ 5] += r1.y*hv; am[ 6] += r1.z*hv; am[ 7] += r1.w*hv;
            am[ 8] += r2.x*hv; am[ 9] += r2.y*hv; am[10] += r2.z*hv; am[11] += r2.w*hv;
            am[12] += r3.x*hv; am[13] += r3.y*hv; am[14] += r3.z*hv; am[15] += r3.w*hv;
        }
        float acc = bfc2[0];
#pragma unroll
        for (int m = 0; m < 16; ++m) {
            float a = am[m];
            a += __shfl_xor(a, 1); a += __shfl_xor(a, 2);
            acc += fmaxf(a + bfc1[m], 0.0f) * Wfc2[m];
        }
        if (s == 0 && nA < N) out[nA] = acc;
    }
    {
        float am[16];
#pragma unroll
        for (int m = 0; m < 16; ++m) am[m] = 0.0f;
#pragma unroll 1
        for (int kk = 0; kk < 8; ++kk) {
            const float* row = Wfc1 + (size_t)(so8 + kk) * 16;
            const float4 r0 = ((const float4*)row)[0];
            const float4 r1 = ((const float4*)row)[1];
            const float4 r2 = ((const float4*)row)[2];
            const float4 r3 = ((const float4*)row)[3];
            const float hv = h1B[kk];
            am[ 0] += r0.x*hv; am[ 1] += r0.y*hv; am[ 2] += r0.z*hv; am[ 3] += r0.w*hv;
            am[ 4] += r1.x*hv; am[ 5] += r1.y*hv; am[ 6] += r1.z*hv; am[ 7] += r1.w*hv;
            am[ 8] += r2.x*hv; am[ 9] += r2.y*hv; am[10] += r2.z*hv; am[11] += r2.w*hv;
            am[12] += r3.x*hv; am[13] += r3.y*hv; am[14] += r3.z*hv; am[15] += r3.w*hv;
        }
        float acc = bfc2[0];
#pragma unroll
        for (int m = 0; m < 16; ++m) {
            float a = am[m];
            a += __shfl_xor(a, 1); a += __shfl_xor(a, 2);
            acc += fmaxf(a + bfc1[m], 0.0f) * Wfc2[m];
        }
        if (s == 0 && nB < N) out[nB] = acc;
    }
}

extern "C" void kernel_launch(void* const* d_in, const int* in_sizes, int n_in,
                              void* d_out, int out_size, void* d_ws, size_t ws_size,
                              hipStream_t stream) {
    (void)n_in; (void)out_size; (void)ws_size;
    // setup_inputs() order:
    // 0 x, 1 edge_index, 2 W_fp, 3 b_fp, 4 W_g1, 5 b_g1, 6 W_g2, 7 b_g2,
    // 8 W_g3, 9 b_g3, 10 W_tp, 11 b_tp, 12 Wih0, 13 Whh0, 14 bih0, 15 bhh0,
    // 16 Wih1, 17 Whh1, 18 bih1, 19 bhh1, 20 W_fc1, 21 b_fc1, 22 W_fc2, 23 b_fc2
    const float* x    = (const float*)d_in[0];
    const float* Wtp  = (const float*)d_in[10];
    const float* btp  = (const float*)d_in[11];
    const float* Wih0 = (const float*)d_in[12];
    const float* Whh0 = (const float*)d_in[13];
    const float* bih0 = (const float*)d_in[14];
    const float* bhh0 = (const float*)d_in[15];
    const float* Wih1 = (const float*)d_in[16];
    const float* Whh1 = (const float*)d_in[17];
    const float* bih1 = (const float*)d_in[18];
    const float* bhh1 = (const float*)d_in[19];
    const float* Wfc1 = (const float*)d_in[20];
    const float* bfc1 = (const float*)d_in[21];
    const float* Wfc2 = (const float*)d_in[22];
    const float* bfc2 = (const float*)d_in[23];

    float* out = (float*)d_out;
    float* pre = (float*)d_ws;   // 384 floats (repacked per-j layout)

    const int N = in_sizes[0] / 64;

    precomp_kernel<<<1, 128, 0, stream>>>(Wih0, Wtp, btp, bih0, bhh0, bih1, bhh1, pre);
    lstm_kernel<<<(N + NPB - 1) / NPB, BS, 0, stream>>>(
        x, Whh0, Wih1, Whh1, Wfc1, bfc1, Wfc2, bfc2, pre, out, N);
}

// Round 23
// 1239.185 us; speedup vs baseline: 2.3248x; 1.2192x over previous
//
#include <hip/hip_runtime.h>

// Only the temporal (LSTM) branch of the reference reaches the output
// (h_gcn is dead). Per node:
//   xt_s = x[n, 52+s] * W_tp + b_tp          (rank-1, folded into A0/C0)
//   2-layer LSTM (H=32, T=12, torch gate order i,f,g,o)
//   out[n] = relu(h1 @ W_fc1 + b_fc1) @ W_fc2 + b_fc2
//
// v14 = v10 REVERT (measured 1242 us in round 17, the session optimum).
// Design-space ledger (22 rounds, counter-verified):
//   - v10 (this kernel): quad k-split, reduce-scatter gate-finish,
//     gate-major 16-load windows, c-state in LDS columns. VGPR=104,
//     no spill, busy 708 us, ~90% of its ~1125 us LDS-instruction
//     floor (4 FMA per ds_read_b128 at ~12 cyc/CU each).
//   - 8-FMA/load variants (v11/v12/v13): stream proven at 630-675 us
//     busy but register envelope (state 48 + window + partials) never
//     fits the 4-wave tier: 168 / spill / 152 VGPR. Line closed.
//   - j-split across waves (v4/v6/v7): allocator remats LDS-provenance
//     h-state into per-use reads at >=256-thread blocks; hints and asm
//     pins don't override. Line closed.
//   - scalar-weight 1-node/thread (v1): grid-limited (1563 waves =
//     1.5/SIMD), 1665 us. Line closed.
// Compiler rules learned: BS=512 hard-caps VGPR at 128 (spills if need
// exceeds); __launch_bounds__ min-waves is ignored both as permission
// (v6) and as cap (v13); keep natural need <= ~120.
// (Resubmission: round-22 bench failed on GPU acquisition.)

#define TSTEPS 12
#define BS 512               // 8 waves per block
#define NPB (BS / 4)         // 128 nodes per block

__device__ __forceinline__ float fsig(float x) {
    float e = __expf(-x);                      // v_exp path; e in [0, inf)
    return __builtin_amdgcn_rcpf(1.0f + e);    // 1/(1+e), ~1 ulp
}

__device__ __forceinline__ float ftanh(float x) {
    float ax = fabsf(x);
    float e = __expf(-2.0f * ax);              // in (0,1], no overflow
    float r = (1.0f - e) * __builtin_amdgcn_rcpf(1.0f + e);
    return x < 0.0f ? -r : r;
}

// Repacked fold of layer-0 input matmul + biases, per OUTPUT j:
//   ws[j*8 + {0..3}] = A0 for gates i,f,g,o of j   (A0[r]=dot(Wih0[r,:],W_tp))
//   ws[j*8 + {4..7}] = C0 for gates i,f,g,o of j   (C0[r]=dot(Wih0[r,:],b_tp)+bih0[r]+bhh0[r])
//   ws[256 + j*4 + {0..3}] = C1 gates i,f,g,o      (bih1[r]+bhh1[r])
// where r = gate*32 + j.
__global__ void precomp_kernel(const float* __restrict__ Wih0,
                               const float* __restrict__ Wtp,
                               const float* __restrict__ btp,
                               const float* __restrict__ bih0,
                               const float* __restrict__ bhh0,
                               const float* __restrict__ bih1,
                               const float* __restrict__ bhh1,
                               float* __restrict__ ws) {
    int r = threadIdx.x;   // 0..127
    if (r < 128) {
        float a = 0.0f, c = 0.0f;
#pragma unroll
        for (int k = 0; k < 16; ++k) {
            float w = Wih0[r * 16 + k];
            a += w * Wtp[k];
            c += w * btp[k];
        }
        const int g4 = r >> 5;          // gate 0..3 (i,f,g,o)
        const int j  = r & 31;          // output index
        ws[j * 8 + g4]       = a;
        ws[j * 8 + 4 + g4]   = c + bih0[r] + bhh0[r];
        ws[256 + j * 4 + g4] = bih1[r] + bhh1[r];
    }
}

__device__ __forceinline__ float dot8(const float4 a0, const float4 a1,
                                      const float h[8]) {
    return a0.x*h[0] + a0.y*h[1] + a0.z*h[2] + a0.w*h[3]
         + a1.x*h[4] + a1.y*h[5] + a1.z*h[6] + a1.w*h[7];
}

// Reduce-scatter over a quad: inputs v0..v3 (per-g partials, all lanes),
// returns sum over the 4 lanes of v_s (s = lane&3). hi2=(s&2), hi1=(s&1).
__device__ __forceinline__ float rs4(float v0, float v1, float v2, float v3,
                                     bool hi2, bool hi1) {
    float sa = hi2 ? v0 : v2;     // give away first-of-other-pair
    float ka = hi2 ? v2 : v0;     // keep first-of-own-pair (g = s&2)
    float sb = hi2 ? v1 : v3;
    float kb = hi2 ? v3 : v1;     // g = (s&2)+1
    float u0 = ka + __shfl_xor(sa, 2);
    float u1 = kb + __shfl_xor(sb, 2);
    float sc = hi1 ? u0 : u1;
    float kc = hi1 ? u1 : u0;     // g = s
    return kc + __shfl_xor(sc, 1);
}

// Layer-0 window: two gates (row offsets offA, offB) for all 4 g's.
// 16 ds_read_b128 in flight (64 VGPR), then 8 dot8 (64 FMA), then 2 rs4.
__device__ __forceinline__ void l0pair(const float* __restrict__ sW,
                                       int jj, int so8, int offA, int offB,
                                       const float h[8], bool hi2, bool hi1,
                                       float& SA, float& SB) {
    float4 a0[4], a1[4], b0[4], b1[4];
#pragma unroll
    for (int g = 0; g < 4; ++g) {
        const float* wa = &sW[(g * 8 + jj + offA) * 32 + so8];
        const float* wb = &sW[(g * 8 + jj + offB) * 32 + so8];
        a0[g] = ((const float4*)wa)[0]; a1[g] = ((const float4*)wa)[1];
        b0[g] = ((const float4*)wb)[0]; b1[g] = ((const float4*)wb)[1];
    }
    float pa[4], pb[4];
#pragma unroll
    for (int g = 0; g < 4; ++g) {
        pa[g] = dot8(a0[g], a1[g], h);
        pb[g] = dot8(b0[g], b1[g], h);
    }
    SA = rs4(pa[0], pa[1], pa[2], pa[3], hi2, hi1);
    SB = rs4(pb[0], pb[1], pb[2], pb[3], hi2, hi1);
}

// Layer-1 window: one gate (row offset off), a-part (Wih1.h0) + b-part
// (Whh1.h1) for all 4 g's. 16 loads, 8 dot8, 1 rs4.
__device__ __forceinline__ float l1gate(const float* __restrict__ sW,
                                        int jj, int so8, int off,
                                        const float h0[8], const float h1[8],
                                        bool hi2, bool hi1) {
    float4 a0[4], a1[4], b0[4], b1[4];
#pragma unroll
    for (int g = 0; g < 4; ++g) {
        const float* ax = &sW[4096 + (g * 8 + jj + off) * 32 + so8];
        const float* bx = &sW[8192 + (g * 8 + jj + off) * 32 + so8];
        a0[g] = ((const float4*)ax)[0]; a1[g] = ((const float4*)ax)[1];
        b0[g] = ((const float4*)bx)[0]; b1[g] = ((const float4*)bx)[1];
    }
    float p[4];
#pragma unroll
    for (int g = 0; g < 4; ++g)
        p[g] = dot8(a0[g], a1[g], h0) + dot8(b0[g], b1[g], h1);
    return rs4(p[0], p[1], p[2], p[3], hi2, hi1);
}

__global__ __launch_bounds__(BS) void lstm_kernel(
    const float* __restrict__ x,
    const float* __restrict__ Whh0,   // [128,32]
    const float* __restrict__ Wih1,   // [128,32]
    const float* __restrict__ Whh1,   // [128,32]
    const float* __restrict__ Wfc1,   // [32,16]
    const float* __restrict__ bfc1,   // [16]
    const float* __restrict__ Wfc2,   // [16]
    const float* __restrict__ bfc2,   // [1]
    const float* __restrict__ pre,    // [384] from precomp (repacked)
    float* __restrict__ out, int N)
{
    // 48 KB weights + 2 x 16 KB per-thread c-state columns = 80 KB.
    // 2 blocks/CU by LDS == 2 blocks/CU by the 128-VGPR tier -> free.
    __shared__ __align__(16) float sW[12288];
    __shared__ float sc0[8 * BS];     // c0, column per thread
    __shared__ float sc1[8 * BS];     // c1

    const int tid = threadIdx.x;
#pragma unroll
    for (int i = 0; i < 8; ++i) sW[i * BS + tid]        = Whh0[i * BS + tid];
#pragma unroll
    for (int i = 0; i < 8; ++i) sW[4096 + i * BS + tid] = Wih1[i * BS + tid];
#pragma unroll
    for (int i = 0; i < 8; ++i) sW[8192 + i * BS + tid] = Whh1[i * BS + tid];
#pragma unroll
    for (int jj = 0; jj < 8; ++jj) {   // own columns only, no extra sync
        sc0[jj * BS + tid] = 0.0f;
        sc1[jj * BS + tid] = 0.0f;
    }
    __syncthreads();                    // only barrier in the kernel

    const int s    = tid & 3;           // k-slice / j-group 0..3
    const int node = tid >> 2;          // 0..127 within block
    const int so8  = s * 8;             // slice base (floats)
    const bool hi2 = (s & 2) != 0;
    const bool hi1 = (s & 1) != 0;
    const int n  = blockIdx.x * NPB + node;
    const int nn = (n < N) ? n : (N > 0 ? N - 1 : 0);
    const float* xr = x + (size_t)nn * 64 + 52;   // last 12 features

    // Per-lane register state: h slices + staged new-h. c lives in LDS.
    float h0r[8], h1r[8], hn[8];
#pragma unroll
    for (int k = 0; k < 8; ++k) { h0r[k] = 0.0f; h1r[k] = 0.0f; }

#pragma unroll 1
    for (int t = 0; t < TSTEPS; ++t) {
        const float xval = xr[t];

        // ---------------- layer 0 ----------------
#pragma unroll
        for (int jj = 0; jj < 8; ++jj) {
            const int jown = so8 + jj;
            float SI, SF, SG, SO;
            l0pair(sW, jj, so8,  0, 32, h0r, hi2, hi1, SI, SF);
            __builtin_amdgcn_sched_barrier(0);
            l0pair(sW, jj, so8, 64, 96, h0r, hi2, hi1, SG, SO);
            __builtin_amdgcn_sched_barrier(0);
            // finish once per j (trans ops overlap next jj's loads)
            const float4 pA = ((const float4*)pre)[jown * 2];       // A0 quad
            const float4 pC = ((const float4*)pre)[jown * 2 + 1];   // C0 quad
            const float gi = SI + pC.x + xval * pA.x;
            const float gf = SF + pC.y + xval * pA.y;
            const float gG = SG + pC.z + xval * pA.z;
            const float go = SO + pC.w + xval * pA.w;
            const int ci = jj * BS + tid;
            const float cc = fsig(gf) * sc0[ci] + fsig(gi) * ftanh(gG);
            sc0[ci] = cc;
            hn[jj]  = fsig(go) * ftanh(cc);
        }
#pragma unroll
        for (int k = 0; k < 8; ++k) h0r[k] = hn[k];   // commit new h0 (regs)

        // ---------------- layer 1 ----------------
#pragma unroll
        for (int jj = 0; jj < 8; ++jj) {
            const int jown = so8 + jj;
            const float SI = l1gate(sW, jj, so8,  0, h0r, h1r, hi2, hi1);
            __builtin_amdgcn_sched_barrier(0);
            const float SF = l1gate(sW, jj, so8, 32, h0r, h1r, hi2, hi1);
            __builtin_amdgcn_sched_barrier(0);
            const float SG = l1gate(sW, jj, so8, 64, h0r, h1r, hi2, hi1);
            __builtin_amdgcn_sched_barrier(0);
            const float SO = l1gate(sW, jj, so8, 96, h0r, h1r, hi2, hi1);
            __builtin_amdgcn_sched_barrier(0);
            const float4 pD = ((const float4*)(pre + 256))[jown];   // C1 quad
            const float gi = SI + pD.x;
            const float gf = SF + pD.y;
            const float gG = SG + pD.z;
            const float go = SO + pD.w;
            const int ci = jj * BS + tid;
            const float cc = fsig(gf) * sc1[ci] + fsig(gi) * ftanh(gG);
            sc1[ci] = cc;
            hn[jj]  = fsig(go) * ftanh(cc);
        }
#pragma unroll
        for (int k = 0; k < 8; ++k) h1r[k] = hn[k];   // commit new h1 (regs)
    }

    // epilogue: relu(h1 @ Wfc1 + bfc1) @ Wfc2 + bfc2 (h1 sliced over quad)
    float am[16];
#pragma unroll
    for (int m = 0; m < 16; ++m) am[m] = 0.0f;
#pragma unroll 1
    for (int kk = 0; kk < 8; ++kk) {
        const float* row = Wfc1 + (size_t)(so8 + kk) * 16;
        const float4 r0 = ((const float4*)row)[0];
        const float4 r1 = ((const float4*)row)[1];
        const float4 r2 = ((const float4*)row)[2];
        const float4 r3 = ((const float4*)row)[3];
        const float hv = h1r[kk];
        am[ 0] += r0.x*hv; am[ 1] += r0.y*hv; am[ 2] += r0.z*hv; am[ 3] += r0.w*hv;
        am[ 4] += r1.x*hv; am[ 5] += r1.y*hv; am[ 6] += r1.z*hv; am[ 7] += r1.w*hv;
        am[ 8] += r2.x*hv; am[ 9] += r2.y*hv; am[10] += r2.z*hv; am[11] += r2.w*hv;
        am[12] += r3.x*hv; am[13] += r3.y*hv; am[14] += r3.z*hv; am[15] += r3.w*hv;
    }
    float acc = bfc2[0];
#pragma unroll
    for (int m = 0; m < 16; ++m) {
        float a = am[m];
        a += __shfl_xor(a, 1); a += __shfl_xor(a, 2);
        acc += fmaxf(a + bfc1[m], 0.0f) * Wfc2[m];
    }
    if (s == 0 && n < N) out[n] = acc;
}

extern "C" void kernel_launch(void* const* d_in, const int* in_sizes, int n_in,
                              void* d_out, int out_size, void* d_ws, size_t ws_size,
                              hipStream_t stream) {
    (void)n_in; (void)out_size; (void)ws_size;
    // setup_inputs() order:
    // 0 x, 1 edge_index, 2 W_fp, 3 b_fp, 4 W_g1, 5 b_g1, 6 W_g2, 7 b_g2,
    // 8 W_g3, 9 b_g3, 10 W_tp, 11 b_tp, 12 Wih0, 13 Whh0, 14 bih0, 15 bhh0,
    // 16 Wih1, 17 Whh1, 18 bih1, 19 bhh1, 20 W_fc1, 21 b_fc1, 22 W_fc2, 23 b_fc2
    const float* x    = (const float*)d_in[0];
    const float* Wtp  = (const float*)d_in[10];
    const float* btp  = (const float*)d_in[11];
    const float* Wih0 = (const float*)d_in[12];
    const float* Whh0 = (const float*)d_in[13];
    const float* bih0 = (const float*)d_in[14];
    const float* bhh0 = (const float*)d_in[15];
    const float* Wih1 = (const float*)d_in[16];
    const float* Whh1 = (const float*)d_in[17];
    const float* bih1 = (const float*)d_in[18];
    const float* bhh1 = (const float*)d_in[19];
    const float* Wfc1 = (const float*)d_in[20];
    const float* bfc1 = (const float*)d_in[21];
    const float* Wfc2 = (const float*)d_in[22];
    const float* bfc2 = (const float*)d_in[23];

    float* out = (float*)d_out;
    float* pre = (float*)d_ws;   // 384 floats (repacked per-j layout)

    const int N = in_sizes[0] / 64;

    precomp_kernel<<<1, 128, 0, stream>>>(Wih0, Wtp, btp, bih0, bhh0, bih1, bhh1, pre);
    lstm_kernel<<<(N + NPB - 1) / NPB, BS, 0, stream>>>(
        x, Whh0, Wih1, Whh1, Wfc1, bfc1, Wfc2, bfc2, pre, out, N);
}